// Round 15
// baseline (122.146 us; speedup 1.0000x reference)
//
#include <hip/hip_runtime.h>
#include <math.h>
#include <float.h>

#define NB 4096
#define ND 256
#define NK 25
#define EPSF 1e-8f
#define CAP 256          // candidate capacity (4 slots/lane)

typedef __attribute__((ext_vector_type(8))) short bf16x8;
typedef __attribute__((ext_vector_type(4))) float f32x4;

#define GLD_LDS16(gp, lp)                                                   \
    __builtin_amdgcn_global_load_lds(                                       \
        (const __attribute__((address_space(1))) void*)(uintptr_t)(gp),     \
        (__attribute__((address_space(3))) void*)(uint32_t)(uintptr_t)(lp), \
        16, 0, 0)

__device__ inline short f2bf(float x) {
    unsigned u = __float_as_uint(x);
    return (short)((u + 0x7FFF + ((u >> 16) & 1)) >> 16);
}

// ---------------------------------------------------------------- prep: bf16 cast + ||f||^2
__global__ __launch_bounds__(64) void prep_kernel(const float* __restrict__ f,
                                                  short* __restrict__ fh,
                                                  float* __restrict__ sq) {
    int row  = blockIdx.x;
    int lane = threadIdx.x;
    float4 v = ((const float4*)(f + (size_t)row * ND))[lane];
    float acc = v.x * v.x + v.y * v.y + v.z * v.z + v.w * v.w;
    *(short4*)(fh + (size_t)row * ND + lane * 4) =
        make_short4(f2bf(v.x), f2bf(v.y), f2bf(v.z), f2bf(v.w));
#pragma unroll
    for (int off = 32; off; off >>= 1) acc += __shfl_down(acc, off);
    if (lane == 0) sq[row] = acc;
}

// ---------------------------------------------------------------- mstat: closed-form per-row threshold
__global__ __launch_bounds__(256) void mstat_kernel(const float* __restrict__ sq,
                                                    float* __restrict__ T) {
    int tid = threadIdx.x;
    __shared__ float r1[4], r2[4];
    float a1 = 0.f, a2 = 0.f;
    for (int t = tid; t < NB; t += 256) { float s = sq[t]; a1 += s; a2 += s * s; }
#pragma unroll
    for (int off = 32; off; off >>= 1) { a1 += __shfl_xor(a1, off); a2 += __shfl_xor(a2, off); }
    if ((tid & 63) == 0) { r1[tid >> 6] = a1; r2[tid >> 6] = a2; }
    __syncthreads();
    float M1 = (r1[0] + r1[1] + r1[2] + r1[3]) * (1.0f / NB);
    float M2 = (r2[0] + r2[1] + r2[2] + r2[3]) * (1.0f / NB);
    float varsq = fmaxf(M2 - M1 * M1, 0.f);
    for (int t = tid; t < NB; t += 256) {
        float s = sq[t];
        T[t] = s + M1 - 2.0f * sqrtf(varsq + 4.f * s);   // mu_i - 2*sigma_i
    }
}

// ---------------------------------------------------------------- MFMA Gram (hi-only, K=256) + dist epilogue
#define BM 128
#define BK 64
__global__ __launch_bounds__(256) void gram_kernel(const short* __restrict__ fh,
                                                   const float* __restrict__ sq,
                                                   float* __restrict__ dist) {
    __shared__ __align__(16) short As[BM * BK];
    __shared__ __align__(16) short Bs[BM * BK];
    int b   = blockIdx.x;
    int ti  = (b >> 5) * BM;
    int tj  = (b & 31) * BM;
    int tid = threadIdx.x;
    int w = tid >> 6, lane = tid & 63;
    int wr = w >> 1, wc = w & 1;
    int fr = lane & 15, fq = lane >> 4;

    f32x4 acc[4][4];
#pragma unroll
    for (int m = 0; m < 4; ++m)
#pragma unroll
        for (int n = 0; n < 4; ++n) acc[m][n] = (f32x4){0.f, 0.f, 0.f, 0.f};

    int srow = lane >> 3;
    int scol = (lane & 7) * 8;

    for (int s = 0; s < 4; ++s) {
        int k0 = s * 64;
#pragma unroll
        for (int i = 0; i < 4; ++i) {
            int c   = 4 * w + i;
            int row = c * 8 + srow;
            GLD_LDS16(fh + (size_t)(ti + row) * ND + k0 + scol, As + c * 512);
            GLD_LDS16(fh + (size_t)(tj + row) * ND + k0 + scol, Bs + c * 512);
        }
        __syncthreads();
#pragma unroll
        for (int kk = 0; kk < 2; ++kk) {
            bf16x8 af[4], bfr[4];
#pragma unroll
            for (int m = 0; m < 4; ++m)
                af[m] = *(const bf16x8*)(As + (wr * 64 + m * 16 + fr) * 64 + kk * 32 + fq * 8);
#pragma unroll
            for (int n = 0; n < 4; ++n)
                bfr[n] = *(const bf16x8*)(Bs + (wc * 64 + n * 16 + fr) * 64 + kk * 32 + fq * 8);
#pragma unroll
            for (int m = 0; m < 4; ++m)
#pragma unroll
                for (int n = 0; n < 4; ++n)
                    acc[m][n] = __builtin_amdgcn_mfma_f32_16x16x32_bf16(af[m], bfr[n], acc[m][n], 0, 0, 0);
        }
        __syncthreads();
    }

#pragma unroll
    for (int m = 0; m < 4; ++m) {
#pragma unroll
        for (int j = 0; j < 4; ++j) {
            int gi = ti + wr * 64 + m * 16 + fq * 4 + j;
            float si = sq[gi];
            float* drow = dist + (size_t)gi * NB + tj + wc * 64;
#pragma unroll
            for (int n = 0; n < 4; ++n) {
                float d = si + sq[tj + wc * 64 + n * 16 + fr] - 2.f * acc[m][n][j];
                drow[n * 16 + fr] = fmaxf(d, 0.f);
            }
        }
    }
}

// ---------------------------------------------------------------- topk7: single-pass stream filter + rank select
__global__ __launch_bounds__(256) void topk7_kernel(const float* __restrict__ dist,
                                                    const float* __restrict__ T,
                                                    int* __restrict__ idxk,
                                                    float* __restrict__ dk,
                                                    float* __restrict__ sigma) {
    int wid  = threadIdx.x >> 6;
    int lane = threadIdx.x & 63;
    int row  = blockIdx.x * 4 + wid;
    __shared__ float cval[4][CAP];
    __shared__ int   cidx[4][CAP];

    const float4* src = (const float4*)(dist + (size_t)row * NB);
    float Tr = T[row];
    unsigned long long ltmask = (1ull << lane) - 1ull;

    // single streaming pass: filter + ballot compaction (no register row copy)
    int cnt = 0;
#pragma unroll 4
    for (int c4 = 0; c4 < 16; ++c4) {
        float4 q = src[c4 * 64 + lane];
        float xs[4] = {q.x, q.y, q.z, q.w};
#pragma unroll
        for (int e = 0; e < 4; ++e) {
            bool p = (xs[e] < Tr);
            unsigned long long m = __ballot(p);
            if (p) {
                int pos = cnt + __popcll(m & ltmask);
                if (pos < CAP) {
                    cval[wid][pos] = xs[e];
                    cidx[wid][pos] = (c4 * 64 + lane) * 4 + e;
                }
            }
            cnt += __popcll(m);
        }
    }

    // fallback (rare): bisection on re-streamed row (L2-hot), then recompact
    if (cnt < NK || cnt > CAP) {
        float s1 = 0.f, mx = 0.f;
        for (int c4 = 0; c4 < 16; ++c4) {
            float4 q = src[c4 * 64 + lane];
            s1 += q.x + q.y + q.z + q.w;
            mx = fmaxf(mx, fmaxf(fmaxf(q.x, q.y), fmaxf(q.z, q.w)));
        }
#pragma unroll
        for (int off = 32; off; off >>= 1) {
            s1 += __shfl_xor(s1, off);
            mx  = fmaxf(mx, __shfl_xor(mx, off));
        }
        float mu = s1 * (1.0f / NB);
        float lo = 0.f, hi = mu;
        int cnt_hi = 0;
        for (int c4 = 0; c4 < 16; ++c4) {
            float4 q = src[c4 * 64 + lane];
            cnt_hi += (q.x < mu) + (q.y < mu) + (q.z < mu) + (q.w < mu);
        }
#pragma unroll
        for (int off = 32; off; off >>= 1) cnt_hi += __shfl_xor(cnt_hi, off);
        if (cnt_hi < NK) { hi = mx * 1.000001f + 1e-20f; cnt_hi = NB; }
        for (int it = 0; it < 40; ++it) {
            if (cnt_hi >= NK && cnt_hi <= CAP) break;
            float mid = 0.5f * (lo + hi);
            if (mid <= lo || mid >= hi) break;
            int cc = 0;
            for (int c4 = 0; c4 < 16; ++c4) {
                float4 q = src[c4 * 64 + lane];
                cc += (q.x < mid) + (q.y < mid) + (q.z < mid) + (q.w < mid);
            }
#pragma unroll
            for (int off = 32; off; off >>= 1) cc += __shfl_xor(cc, off);
            if (cc >= NK) { hi = mid; cnt_hi = cc; } else { lo = mid; }
        }
        Tr = hi;
        cnt = 0;
        for (int c4 = 0; c4 < 16; ++c4) {
            float4 q = src[c4 * 64 + lane];
            float xs[4] = {q.x, q.y, q.z, q.w};
#pragma unroll
            for (int e = 0; e < 4; ++e) {
                bool p = (xs[e] < Tr);
                unsigned long long m = __ballot(p);
                if (p) {
                    int pos = cnt + __popcll(m & ltmask);
                    if (pos < CAP) {
                        cval[wid][pos] = xs[e];
                        cidx[wid][pos] = (c4 * 64 + lane) * 4 + e;
                    }
                }
                cnt += __popcll(m);
            }
        }
        cnt = min(cnt, CAP);
    }

    // exact rank-select by (value,index) over <=256 candidates, 4 slots/lane
    int slots = (cnt + 63) >> 6;
    float x[4]; int xi[4];
#pragma unroll
    for (int k = 0; k < 4; ++k) {
        int p = lane + 64 * k;
        if (p < cnt) { x[k] = cval[wid][p]; xi[k] = cidx[wid][p]; }
        else         { x[k] = FLT_MAX;      xi[k] = 0x7fffffff; }
    }
    int rank[4] = {0, 0, 0, 0};
    for (int s = 0; s < 64; ++s) {
        int sl = (lane + s) & 63;
#pragma unroll
        for (int k2 = 0; k2 < 4; ++k2) {
            if (k2 < slots) {
                float y  = __shfl(x[k2], sl);
                int   yi = __shfl(xi[k2], sl);
#pragma unroll
                for (int k = 0; k < 4; ++k) {
                    if (k < slots) {
                        bool lt = (y < x[k]) || (y == x[k] && yi < xi[k]);
                        rank[k] += lt ? 1 : 0;
                    }
                }
            }
        }
    }
    float t = 0.f;
#pragma unroll
    for (int k = 0; k < 4; ++k) {
        if (k < slots && x[k] != FLT_MAX && rank[k] < NK) {
            idxk[row * NK + rank[k]] = xi[k];
            dk[row * NK + rank[k]]   = x[k];
            t += sqrtf(x[k] + EPSF);
        }
    }
#pragma unroll
    for (int off = 32; off; off >>= 1) t += __shfl_xor(t, off);
    if (lane == 0) sigma[row] = t * (1.0f / NK);
}

// ---------------------------------------------------------------- P rows + score-sorted prefix tables
__global__ __launch_bounds__(64) void buildp_kernel(const int* __restrict__ idxk,
                                                    const float* __restrict__ dk,
                                                    const float* __restrict__ sigma,
                                                    const int* __restrict__ labels,
                                                    const float* __restrict__ scores,
                                                    float* __restrict__ pval,
                                                    float* __restrict__ bs,
                                                    float2* __restrict__ cs) {
    int row  = blockIdx.x;
    int lane = threadIdx.x;
    __shared__ float sb[32];
    __shared__ float sp[32];

    float w = 0.f;
    int j = 0;
    if (lane < NK) {
        j = idxk[row * NK + lane];
        bool mut = false;
        for (int n = 0; n < NK; ++n) mut |= (idxk[j * NK + n] == row);
        bool dir = labels[row] <= labels[j];
        float sij = sigma[row] * sigma[j] + EPSF;
        w = (mut && dir) ? expf(-dk[row * NK + lane] / sij) : 0.f;
        if (j == row) w += 1.f;
    }
    float rs = w;
#pragma unroll
    for (int off = 32; off; off >>= 1) rs += __shfl_down(rs, off);
    rs = __shfl(rs, 0);
    float pv = (lane < NK) ? w / (rs + EPSF) : 0.f;
    if (lane < NK) pval[row * NK + lane] = pv;

    float sj = (lane < NK) ? scores[j] : FLT_MAX;
    int rank = 0;
#pragma unroll
    for (int u = 0; u < NK; ++u) {
        float su = __shfl(sj, u);
        rank += (su < sj || (su == sj && u < lane)) ? 1 : 0;
    }
    if (lane < 32) { sb[lane] = FLT_MAX; sp[lane] = 0.f; }
    __syncthreads();
    if (lane < NK) { sb[rank] = sj; sp[rank] = pv; }
    __syncthreads();

    float b = sb[lane & 31];
    float p = sp[lane & 31];
    float c  = p;
    float s2 = p * b;
#pragma unroll
    for (int off = 1; off < 32; off <<= 1) {
        float oc = __shfl_up(c, off);
        float os = __shfl_up(s2, off);
        if (lane >= off) { c += oc; s2 += os; }
    }
    float ce = __shfl_up(c, 1);
    float se = __shfl_up(s2, 1);
    if (lane == 0) { ce = 0.f; se = 0.f; }
    if (lane < 32) {
        bs[row * 32 + lane] = b;
        cs[row * 32 + lane] = make_float2(ce, se);
    }
}

// ---------------------------------------------------------------- hval: per-j G/H at the 25 needed points
__global__ __launch_bounds__(256) void hval_kernel(const int* __restrict__ idxk,
                                                   const float* __restrict__ pval,
                                                   const float* __restrict__ scores,
                                                   const float* __restrict__ bs,
                                                   const float2* __restrict__ cs,
                                                   float* __restrict__ Gval,
                                                   float* __restrict__ Hval) {
    int wid  = threadIdx.x >> 6;
    int lane = threadIdx.x & 63;
    int j    = blockIdx.x * 4 + wid;
    __shared__ float2 slab[4][NK][26];

    int  ln = (lane < NK) ? lane : NK - 1;
    int  q  = idxk[j * NK + ln];
    float p = (lane < NK) ? pval[j * NK + lane] : 0.f;
    float sqv = scores[q];

    float4 bq[7];
    const float4* b4 = (const float4*)(bs + q * 32);
#pragma unroll
    for (int t = 0; t < 7; ++t) bq[t] = b4[t];
    const float4* c4 = (const float4*)(cs + q * 32);
    if (lane < NK) {
#pragma unroll
        for (int t = 0; t < 13; ++t)
            *(float4*)&slab[wid][lane][t * 2] = c4[t];
    }

    float bjj = bs[j * 32 + lane];
    int posj = 0;
#pragma unroll
    for (int r = 0; r < NK; ++r)
        posj += (__shfl(bjj, r) < sqv) ? 1 : 0;
    float2 cj = cs[j * 32 + posj];
    if (lane < NK) Gval[j * 32 + lane] = sqv * cj.x - cj.y;

    __syncthreads();

    for (int u = 0; u < NK; ++u) {
        float x = __shfl(sqv, u);
        int pos = 0;
#pragma unroll
        for (int t = 0; t < 7; ++t) {
            float4 b = bq[t];
            pos += (b.x < x) + (b.y < x) + (b.z < x) + (b.w < x);
        }
        float2 ch = slab[wid][ln][pos];
        float g = p * (x * ch.x - ch.y);
#pragma unroll
        for (int off = 32; off; off >>= 1) g += __shfl_xor(g, off);
        if (lane == 0) Hval[j * 32 + u] = g;
    }
}

// ---------------------------------------------------------------- final loss: per-wave partial
__global__ __launch_bounds__(256) void loss_kernel(const float* __restrict__ scores,
                                                   const int* __restrict__ idxk,
                                                   const float* __restrict__ pval,
                                                   const float* __restrict__ Gval,
                                                   const float* __restrict__ Hval,
                                                   float* __restrict__ partial) {
    int wid  = threadIdx.x >> 6;
    int lane = threadIdx.x & 63;
    int i    = blockIdx.x * 4 + wid;
    float si = scores[i];
    float acc = 0.f;
    if (lane < NK) {
        int   jm = idxk[i * NK + lane];
        float pm = pval[i * NK + lane];
        float sj = scores[jm];
        int slot = -1;
        const int* row = idxk + jm * NK;
#pragma unroll
        for (int n = 0; n < NK; ++n)
            if (row[n] == i) slot = n;
        float g = 0.f, h = 0.f;
        if (slot >= 0) {
            g = Gval[jm * 32 + slot];
            h = Hval[jm * 32 + slot];
        }
        acc = pm * (fmaxf(si - sj, 0.f) + 0.5f * g + (1.f / 3.f) * h);
    }
#pragma unroll
    for (int off = 32; off; off >>= 1) acc += __shfl_xor(acc, off);
    if (lane == 0) partial[i] = acc;
}

// ---------------------------------------------------------------- final reduce
__global__ __launch_bounds__(256) void reduce_kernel(const float* __restrict__ partial,
                                                     float* __restrict__ out) {
    int tid = threadIdx.x;
    __shared__ float red[4];
    float a = 0.f;
    for (int t = tid; t < NB / 4; t += 256) {
        float4 p = ((const float4*)partial)[t];
        a += p.x + p.y + p.z + p.w;
    }
#pragma unroll
    for (int off = 32; off; off >>= 1) a += __shfl_xor(a, off);
    if ((tid & 63) == 0) red[tid >> 6] = a;
    __syncthreads();
    if (tid == 0) out[0] = (red[0] + red[1] + red[2] + red[3]) * (1.0f / NB);
}

// ---------------------------------------------------------------- launch
extern "C" void kernel_launch(void* const* d_in, const int* in_sizes, int n_in,
                              void* d_out, int out_size, void* d_ws, size_t ws_size,
                              hipStream_t stream) {
    const float* features = (const float*)d_in[0];
    const float* scores   = (const float*)d_in[1];
    const int*   labels   = (const int*)d_in[2];
    float* out = (float*)d_out;

    char* ws = (char*)d_ws;
    size_t off = 0;
    float*  dist    = (float*) (ws + off); off += (size_t)NB * NB * 4;   // 64 MB
    short*  fh      = (short*) (ws + off); off += (size_t)NB * ND * 2;   // 2 MB
    float*  sq      = (float*) (ws + off); off += (size_t)NB * 4;
    float*  T       = (float*) (ws + off); off += (size_t)NB * 4;
    int*    idxk    = (int*)   (ws + off); off += (size_t)NB * NK * 4;
    float*  dk      = (float*) (ws + off); off += (size_t)NB * NK * 4;
    float*  sigma   = (float*) (ws + off); off += (size_t)NB * 4;
    float*  pval    = (float*) (ws + off); off += (size_t)NB * NK * 4;
    float*  bs      = (float*) (ws + off); off += (size_t)NB * 32 * 4;
    float2* cs      = (float2*)(ws + off); off += (size_t)NB * 32 * 8;
    float*  Gval    = (float*) (ws + off); off += (size_t)NB * 32 * 4;
    float*  Hval    = (float*) (ws + off); off += (size_t)NB * 32 * 4;
    float*  partial = (float*) (ws + off); off += (size_t)NB * 4;

    prep_kernel<<<NB, 64, 0, stream>>>(features, fh, sq);
    mstat_kernel<<<1, 256, 0, stream>>>(sq, T);
    gram_kernel<<<(NB / BM) * (NB / BM), 256, 0, stream>>>(fh, sq, dist);
    topk7_kernel<<<NB / 4, 256, 0, stream>>>(dist, T, idxk, dk, sigma);
    buildp_kernel<<<NB, 64, 0, stream>>>(idxk, dk, sigma, labels, scores, pval, bs, cs);
    hval_kernel<<<NB / 4, 256, 0, stream>>>(idxk, pval, scores, bs, cs, Gval, Hval);
    loss_kernel<<<NB / 4, 256, 0, stream>>>(scores, idxk, pval, Gval, Hval, partial);
    reduce_kernel<<<1, 256, 0, stream>>>(partial, out);
}

// Round 16
// 113.175 us; speedup vs baseline: 1.0793x; 1.0793x over previous
//
#include <hip/hip_runtime.h>
#include <math.h>
#include <float.h>

#define NB 4096
#define ND 256
#define NK 25
#define EPSF 1e-8f
#define CAP 256          // candidate capacity (1 per thread)

typedef __attribute__((ext_vector_type(8))) short bf16x8;
typedef __attribute__((ext_vector_type(4))) float f32x4;

#define GLD_LDS16(gp, lp)                                                   \
    __builtin_amdgcn_global_load_lds(                                       \
        (const __attribute__((address_space(1))) void*)(uintptr_t)(gp),     \
        (__attribute__((address_space(3))) void*)(uint32_t)(uintptr_t)(lp), \
        16, 0, 0)

__device__ inline short f2bf(float x) {
    unsigned u = __float_as_uint(x);
    return (short)((u + 0x7FFF + ((u >> 16) & 1)) >> 16);
}

// ---------------------------------------------------------------- prep: bf16 cast + ||f||^2
__global__ __launch_bounds__(64) void prep_kernel(const float* __restrict__ f,
                                                  short* __restrict__ fh,
                                                  float* __restrict__ sq) {
    int row  = blockIdx.x;
    int lane = threadIdx.x;
    float4 v = ((const float4*)(f + (size_t)row * ND))[lane];
    float acc = v.x * v.x + v.y * v.y + v.z * v.z + v.w * v.w;
    *(short4*)(fh + (size_t)row * ND + lane * 4) =
        make_short4(f2bf(v.x), f2bf(v.y), f2bf(v.z), f2bf(v.w));
#pragma unroll
    for (int off = 32; off; off >>= 1) acc += __shfl_down(acc, off);
    if (lane == 0) sq[row] = acc;
}

// ---------------------------------------------------------------- mstat: closed-form per-row threshold
__global__ __launch_bounds__(256) void mstat_kernel(const float* __restrict__ sq,
                                                    float* __restrict__ T) {
    int tid = threadIdx.x;
    __shared__ float r1[4], r2[4];
    float a1 = 0.f, a2 = 0.f;
    for (int t = tid; t < NB; t += 256) { float s = sq[t]; a1 += s; a2 += s * s; }
#pragma unroll
    for (int off = 32; off; off >>= 1) { a1 += __shfl_xor(a1, off); a2 += __shfl_xor(a2, off); }
    if ((tid & 63) == 0) { r1[tid >> 6] = a1; r2[tid >> 6] = a2; }
    __syncthreads();
    float M1 = (r1[0] + r1[1] + r1[2] + r1[3]) * (1.0f / NB);
    float M2 = (r2[0] + r2[1] + r2[2] + r2[3]) * (1.0f / NB);
    float varsq = fmaxf(M2 - M1 * M1, 0.f);
    for (int t = tid; t < NB; t += 256) {
        float s = sq[t];
        T[t] = s + M1 - 2.0f * sqrtf(varsq + 4.f * s);   // mu_i - 2*sigma_i
    }
}

// ---------------------------------------------------------------- MFMA Gram (hi-only, K=256) + dist epilogue
#define BM 128
#define BK 64
__global__ __launch_bounds__(256) void gram_kernel(const short* __restrict__ fh,
                                                   const float* __restrict__ sq,
                                                   float* __restrict__ dist) {
    __shared__ __align__(16) short As[BM * BK];
    __shared__ __align__(16) short Bs[BM * BK];
    int b   = blockIdx.x;
    int ti  = (b >> 5) * BM;
    int tj  = (b & 31) * BM;
    int tid = threadIdx.x;
    int w = tid >> 6, lane = tid & 63;
    int wr = w >> 1, wc = w & 1;
    int fr = lane & 15, fq = lane >> 4;

    f32x4 acc[4][4];
#pragma unroll
    for (int m = 0; m < 4; ++m)
#pragma unroll
        for (int n = 0; n < 4; ++n) acc[m][n] = (f32x4){0.f, 0.f, 0.f, 0.f};

    int srow = lane >> 3;
    int scol = (lane & 7) * 8;

    for (int s = 0; s < 4; ++s) {
        int k0 = s * 64;
#pragma unroll
        for (int i = 0; i < 4; ++i) {
            int c   = 4 * w + i;
            int row = c * 8 + srow;
            GLD_LDS16(fh + (size_t)(ti + row) * ND + k0 + scol, As + c * 512);
            GLD_LDS16(fh + (size_t)(tj + row) * ND + k0 + scol, Bs + c * 512);
        }
        __syncthreads();
#pragma unroll
        for (int kk = 0; kk < 2; ++kk) {
            bf16x8 af[4], bfr[4];
#pragma unroll
            for (int m = 0; m < 4; ++m)
                af[m] = *(const bf16x8*)(As + (wr * 64 + m * 16 + fr) * 64 + kk * 32 + fq * 8);
#pragma unroll
            for (int n = 0; n < 4; ++n)
                bfr[n] = *(const bf16x8*)(Bs + (wc * 64 + n * 16 + fr) * 64 + kk * 32 + fq * 8);
#pragma unroll
            for (int m = 0; m < 4; ++m)
#pragma unroll
                for (int n = 0; n < 4; ++n)
                    acc[m][n] = __builtin_amdgcn_mfma_f32_16x16x32_bf16(af[m], bfr[n], acc[m][n], 0, 0, 0);
        }
        __syncthreads();
    }

#pragma unroll
    for (int m = 0; m < 4; ++m) {
#pragma unroll
        for (int j = 0; j < 4; ++j) {
            int gi = ti + wr * 64 + m * 16 + fq * 4 + j;
            float si = sq[gi];
            float* drow = dist + (size_t)gi * NB + tj + wc * 64;
#pragma unroll
            for (int n = 0; n < 4; ++n) {
                float d = si + sq[tj + wc * 64 + n * 16 + fr] - 2.f * acc[m][n][j];
                drow[n * 16 + fr] = fmaxf(d, 0.f);
            }
        }
    }
}

// ---------------------------------------------------------------- topk8: block/row, LDS-atomic filter + broadcast rank
__global__ __launch_bounds__(256) void topk8_kernel(const float* __restrict__ dist,
                                                    const float* __restrict__ T,
                                                    int* __restrict__ idxk,
                                                    float* __restrict__ dk,
                                                    float* __restrict__ sigma) {
    int row = blockIdx.x;
    int tid = threadIdx.x;
    __shared__ float cval[CAP];
    __shared__ int   cidx[CAP];
    __shared__ float ssq[NK];
    __shared__ int   s_cnt;
    __shared__ int   red[4];

    if (tid == 0) s_cnt = 0;
    __syncthreads();

    float Tr = T[row];
    const float4* src = (const float4*)(dist + (size_t)row * NB);

    // all 4 loads issued independently, then filter via LDS atomics
    float4 q0 = src[0 * 256 + tid];
    float4 q1 = src[1 * 256 + tid];
    float4 q2 = src[2 * 256 + tid];
    float4 q3 = src[3 * 256 + tid];
    float xs[16] = {q0.x, q0.y, q0.z, q0.w, q1.x, q1.y, q1.z, q1.w,
                    q2.x, q2.y, q2.z, q2.w, q3.x, q3.y, q3.z, q3.w};
#pragma unroll
    for (int e = 0; e < 16; ++e) {
        if (xs[e] < Tr) {
            int pos = atomicAdd(&s_cnt, 1);
            if (pos < CAP) {
                cval[pos] = xs[e];
                cidx[pos] = ((e >> 2) * 256 + tid) * 4 + (e & 3);
            }
        }
    }
    __syncthreads();
    int cnt = s_cnt;

    if (cnt < NK || cnt > CAP) {
        // fallback: block-wide bisection on the (L3-hot) row, then recompact
        float s1 = 0.f, mx = 0.f;
#pragma unroll
        for (int e = 0; e < 16; ++e) { s1 += xs[e]; mx = fmaxf(mx, xs[e]); }
#pragma unroll
        for (int off = 32; off; off >>= 1) { s1 += __shfl_xor(s1, off); mx = fmaxf(mx, __shfl_xor(mx, off)); }
        __syncthreads();
        if ((tid & 63) == 0) { ((float*)red)[tid >> 6] = s1; }
        __syncthreads();
        s1 = ((float*)red)[0] + ((float*)red)[1] + ((float*)red)[2] + ((float*)red)[3];
        __syncthreads();
        if ((tid & 63) == 0) { ((float*)red)[tid >> 6] = mx; }
        __syncthreads();
        mx = fmaxf(fmaxf(((float*)red)[0], ((float*)red)[1]),
                   fmaxf(((float*)red)[2], ((float*)red)[3]));
        float mu = s1 * (1.0f / NB);
        float lo = 0.f, hi = mx * 1.000001f + 1e-20f;
        int cnt_hi = NB;
        for (int it = 0; it < 40; ++it) {
            if (cnt_hi >= NK && cnt_hi <= CAP) break;
            float mid = (cnt_hi > CAP) ? 0.5f * (lo + hi) : mu;  // first iters shrink from mu if helpful
            mid = 0.5f * (lo + hi);
            if (mid <= lo || mid >= hi) break;
            int c = 0;
#pragma unroll
            for (int e = 0; e < 16; ++e) c += (xs[e] < mid) ? 1 : 0;
#pragma unroll
            for (int off = 32; off; off >>= 1) c += __shfl_xor(c, off);
            __syncthreads();
            if ((tid & 63) == 0) red[tid >> 6] = c;
            __syncthreads();
            c = red[0] + red[1] + red[2] + red[3];
            if (c >= NK) { hi = mid; cnt_hi = c; } else { lo = mid; }
            __syncthreads();
        }
        Tr = hi;
        if (tid == 0) s_cnt = 0;
        __syncthreads();
#pragma unroll
        for (int e = 0; e < 16; ++e) {
            if (xs[e] < Tr) {
                int pos = atomicAdd(&s_cnt, 1);
                if (pos < CAP) {
                    cval[pos] = xs[e];
                    cidx[pos] = ((e >> 2) * 256 + tid) * 4 + (e & 3);
                }
            }
        }
        __syncthreads();
        cnt = min(s_cnt, CAP);
    }

    // exact rank-select: thread p owns candidate p; rank via LDS-broadcast loop
    float x  = (tid < cnt) ? cval[tid] : FLT_MAX;
    int   xi = (tid < cnt) ? cidx[tid] : 0x7fffffff;
    int rank = 0;
    for (int r = 0; r < cnt; ++r) {
        float y  = cval[r];
        int   yi = cidx[r];
        rank += (y < x || (y == x && yi < xi)) ? 1 : 0;
    }
    bool sel = (tid < cnt) && (rank < NK);
    if (sel) {
        idxk[row * NK + rank] = xi;
        dk[row * NK + rank]   = x;
        ssq[rank] = sqrtf(x + EPSF);
    }
    __syncthreads();
    if (tid == 0) {
        float t = 0.f;
#pragma unroll
        for (int r = 0; r < NK; ++r) t += ssq[r];    // fixed order: deterministic
        sigma[row] = t * (1.0f / NK);
    }
}

// ---------------------------------------------------------------- P rows + score-sorted prefix tables
__global__ __launch_bounds__(64) void buildp_kernel(const int* __restrict__ idxk,
                                                    const float* __restrict__ dk,
                                                    const float* __restrict__ sigma,
                                                    const int* __restrict__ labels,
                                                    const float* __restrict__ scores,
                                                    float* __restrict__ pval,
                                                    float* __restrict__ bs,
                                                    float2* __restrict__ cs) {
    int row  = blockIdx.x;
    int lane = threadIdx.x;
    __shared__ float sb[32];
    __shared__ float sp[32];

    float w = 0.f;
    int j = 0;
    if (lane < NK) {
        j = idxk[row * NK + lane];
        bool mut = false;
        for (int n = 0; n < NK; ++n) mut |= (idxk[j * NK + n] == row);
        bool dir = labels[row] <= labels[j];
        float sij = sigma[row] * sigma[j] + EPSF;
        w = (mut && dir) ? expf(-dk[row * NK + lane] / sij) : 0.f;
        if (j == row) w += 1.f;
    }
    float rs = w;
#pragma unroll
    for (int off = 32; off; off >>= 1) rs += __shfl_down(rs, off);
    rs = __shfl(rs, 0);
    float pv = (lane < NK) ? w / (rs + EPSF) : 0.f;
    if (lane < NK) pval[row * NK + lane] = pv;

    float sj = (lane < NK) ? scores[j] : FLT_MAX;
    int rank = 0;
#pragma unroll
    for (int u = 0; u < NK; ++u) {
        float su = __shfl(sj, u);
        rank += (su < sj || (su == sj && u < lane)) ? 1 : 0;
    }
    if (lane < 32) { sb[lane] = FLT_MAX; sp[lane] = 0.f; }
    __syncthreads();
    if (lane < NK) { sb[rank] = sj; sp[rank] = pv; }
    __syncthreads();

    float b = sb[lane & 31];
    float p = sp[lane & 31];
    float c  = p;
    float s2 = p * b;
#pragma unroll
    for (int off = 1; off < 32; off <<= 1) {
        float oc = __shfl_up(c, off);
        float os = __shfl_up(s2, off);
        if (lane >= off) { c += oc; s2 += os; }
    }
    float ce = __shfl_up(c, 1);
    float se = __shfl_up(s2, 1);
    if (lane == 0) { ce = 0.f; se = 0.f; }
    if (lane < 32) {
        bs[row * 32 + lane] = b;
        cs[row * 32 + lane] = make_float2(ce, se);
    }
}

// ---------------------------------------------------------------- hval: per-j G/H at the 25 needed points
__global__ __launch_bounds__(256) void hval_kernel(const int* __restrict__ idxk,
                                                   const float* __restrict__ pval,
                                                   const float* __restrict__ scores,
                                                   const float* __restrict__ bs,
                                                   const float2* __restrict__ cs,
                                                   float* __restrict__ Gval,
                                                   float* __restrict__ Hval) {
    int wid  = threadIdx.x >> 6;
    int lane = threadIdx.x & 63;
    int j    = blockIdx.x * 4 + wid;
    __shared__ float2 slab[4][NK][26];

    int  ln = (lane < NK) ? lane : NK - 1;
    int  q  = idxk[j * NK + ln];
    float p = (lane < NK) ? pval[j * NK + lane] : 0.f;
    float sqv = scores[q];

    float4 bq[7];
    const float4* b4 = (const float4*)(bs + q * 32);
#pragma unroll
    for (int t = 0; t < 7; ++t) bq[t] = b4[t];
    const float4* c4 = (const float4*)(cs + q * 32);
    if (lane < NK) {
#pragma unroll
        for (int t = 0; t < 13; ++t)
            *(float4*)&slab[wid][lane][t * 2] = c4[t];
    }

    float bjj = bs[j * 32 + lane];
    int posj = 0;
#pragma unroll
    for (int r = 0; r < NK; ++r)
        posj += (__shfl(bjj, r) < sqv) ? 1 : 0;
    float2 cj = cs[j * 32 + posj];
    if (lane < NK) Gval[j * 32 + lane] = sqv * cj.x - cj.y;

    __syncthreads();

    for (int u = 0; u < NK; ++u) {
        float x = __shfl(sqv, u);
        int pos = 0;
#pragma unroll
        for (int t = 0; t < 7; ++t) {
            float4 b = bq[t];
            pos += (b.x < x) + (b.y < x) + (b.z < x) + (b.w < x);
        }
        float2 ch = slab[wid][ln][pos];
        float g = p * (x * ch.x - ch.y);
#pragma unroll
        for (int off = 32; off; off >>= 1) g += __shfl_xor(g, off);
        if (lane == 0) Hval[j * 32 + u] = g;
    }
}

// ---------------------------------------------------------------- final loss: per-wave partial
__global__ __launch_bounds__(256) void loss_kernel(const float* __restrict__ scores,
                                                   const int* __restrict__ idxk,
                                                   const float* __restrict__ pval,
                                                   const float* __restrict__ Gval,
                                                   const float* __restrict__ Hval,
                                                   float* __restrict__ partial) {
    int wid  = threadIdx.x >> 6;
    int lane = threadIdx.x & 63;
    int i    = blockIdx.x * 4 + wid;
    float si = scores[i];
    float acc = 0.f;
    if (lane < NK) {
        int   jm = idxk[i * NK + lane];
        float pm = pval[i * NK + lane];
        float sj = scores[jm];
        int slot = -1;
        const int* row = idxk + jm * NK;
#pragma unroll
        for (int n = 0; n < NK; ++n)
            if (row[n] == i) slot = n;
        float g = 0.f, h = 0.f;
        if (slot >= 0) {
            g = Gval[jm * 32 + slot];
            h = Hval[jm * 32 + slot];
        }
        acc = pm * (fmaxf(si - sj, 0.f) + 0.5f * g + (1.f / 3.f) * h);
    }
#pragma unroll
    for (int off = 32; off; off >>= 1) acc += __shfl_xor(acc, off);
    if (lane == 0) partial[i] = acc;
}

// ---------------------------------------------------------------- final reduce
__global__ __launch_bounds__(256) void reduce_kernel(const float* __restrict__ partial,
                                                     float* __restrict__ out) {
    int tid = threadIdx.x;
    __shared__ float red[4];
    float a = 0.f;
    for (int t = tid; t < NB / 4; t += 256) {
        float4 p = ((const float4*)partial)[t];
        a += p.x + p.y + p.z + p.w;
    }
#pragma unroll
    for (int off = 32; off; off >>= 1) a += __shfl_xor(a, off);
    if ((tid & 63) == 0) red[tid >> 6] = a;
    __syncthreads();
    if (tid == 0) out[0] = (red[0] + red[1] + red[2] + red[3]) * (1.0f / NB);
}

// ---------------------------------------------------------------- launch
extern "C" void kernel_launch(void* const* d_in, const int* in_sizes, int n_in,
                              void* d_out, int out_size, void* d_ws, size_t ws_size,
                              hipStream_t stream) {
    const float* features = (const float*)d_in[0];
    const float* scores   = (const float*)d_in[1];
    const int*   labels   = (const int*)d_in[2];
    float* out = (float*)d_out;

    char* ws = (char*)d_ws;
    size_t off = 0;
    float*  dist    = (float*) (ws + off); off += (size_t)NB * NB * 4;   // 64 MB
    short*  fh      = (short*) (ws + off); off += (size_t)NB * ND * 2;   // 2 MB
    float*  sq      = (float*) (ws + off); off += (size_t)NB * 4;
    float*  T       = (float*) (ws + off); off += (size_t)NB * 4;
    int*    idxk    = (int*)   (ws + off); off += (size_t)NB * NK * 4;
    float*  dk      = (float*) (ws + off); off += (size_t)NB * NK * 4;
    float*  sigma   = (float*) (ws + off); off += (size_t)NB * 4;
    float*  pval    = (float*) (ws + off); off += (size_t)NB * NK * 4;
    float*  bs      = (float*) (ws + off); off += (size_t)NB * 32 * 4;
    float2* cs      = (float2*)(ws + off); off += (size_t)NB * 32 * 8;
    float*  Gval    = (float*) (ws + off); off += (size_t)NB * 32 * 4;
    float*  Hval    = (float*) (ws + off); off += (size_t)NB * 32 * 4;
    float*  partial = (float*) (ws + off); off += (size_t)NB * 4;

    prep_kernel<<<NB, 64, 0, stream>>>(features, fh, sq);
    mstat_kernel<<<1, 256, 0, stream>>>(sq, T);
    gram_kernel<<<(NB / BM) * (NB / BM), 256, 0, stream>>>(fh, sq, dist);
    topk8_kernel<<<NB, 256, 0, stream>>>(dist, T, idxk, dk, sigma);
    buildp_kernel<<<NB, 64, 0, stream>>>(idxk, dk, sigma, labels, scores, pval, bs, cs);
    hval_kernel<<<NB / 4, 256, 0, stream>>>(idxk, pval, scores, bs, cs, Gval, Hval);
    loss_kernel<<<NB / 4, 256, 0, stream>>>(scores, idxk, pval, Gval, Hval, partial);
    reduce_kernel<<<1, 256, 0, stream>>>(partial, out);
}